// Round 1
// 530.212 us; speedup vs baseline: 1.2076x; 1.2076x over previous
//
#include <hip/hip_runtime.h>
#include <hip/hip_bf16.h>
#include <stdint.h>

// MultiHeadAttention: B=4, S=1024, D=1024, H=16, Dh=64
// d_out = [out (4M fp32)] ++ [attention raw logits (64M fp32)]

typedef __attribute__((ext_vector_type(8))) short v8s;   // 8 x bf16 bits
typedef __attribute__((ext_vector_type(4))) short v4s;   // 4 x bf16 bits
typedef __attribute__((ext_vector_type(4))) float v4f;

#define S_ 1024
#define MTOT 4096
#define LDA 72   // padded LDS row stride (bf16 elems): 144 B -> conflict-light
#define LDP 136  // P-tile LDS row stride (bf16 elems): 272 B

__device__ __forceinline__ unsigned short f2b(float f) {
  union { float f; unsigned int u; } x; x.f = f;
  unsigned int u = x.u + 0x7fffu + ((x.u >> 16) & 1u);  // RNE
  return (unsigned short)(u >> 16);
}

// ---------- cast fp32 -> bf16 for q,k,v in one launch ----------
__global__ __launch_bounds__(256) void cast3_k(
    const float* __restrict__ q, const float* __restrict__ k, const float* __restrict__ v,
    unsigned short* __restrict__ qb, unsigned short* __restrict__ kb, unsigned short* __restrict__ vb) {
  const float* src = blockIdx.y == 0 ? q : blockIdx.y == 1 ? k : v;
  unsigned short* dst = blockIdx.y == 0 ? qb : blockIdx.y == 1 ? kb : vb;
  int i = (blockIdx.x * 256 + threadIdx.x) * 8;
  v4f a = *(const v4f*)(src + i);
  v4f b = *(const v4f*)(src + i + 4);
  union { unsigned short u[8]; v8s v; } o;
  o.u[0] = f2b(a[0]); o.u[1] = f2b(a[1]); o.u[2] = f2b(a[2]); o.u[3] = f2b(a[3]);
  o.u[4] = f2b(b[0]); o.u[5] = f2b(b[1]); o.u[6] = f2b(b[2]); o.u[7] = f2b(b[3]);
  *(v8s*)(dst + i) = o.v;
}

// ---------- transpose + cast W[k][n] -> WT[n][k] bf16 ----------
__global__ __launch_bounds__(256) void transpose_cast_k(
    const float* __restrict__ W0, const float* __restrict__ W1,
    const float* __restrict__ W2, const float* __restrict__ W3,
    unsigned short* __restrict__ T0, unsigned short* __restrict__ T1,
    unsigned short* __restrict__ T2, unsigned short* __restrict__ T3) {
  const float* W = blockIdx.z == 0 ? W0 : blockIdx.z == 1 ? W1 : blockIdx.z == 2 ? W2 : W3;
  unsigned short* T = blockIdx.z == 0 ? T0 : blockIdx.z == 1 ? T1 : blockIdx.z == 2 ? T2 : T3;
  __shared__ float tile[32][33];
  int tx = threadIdx.x & 31, ty = threadIdx.x >> 5;
  int n0 = blockIdx.x * 32, k0 = blockIdx.y * 32;
#pragma unroll
  for (int i = 0; i < 4; i++)
    tile[ty + i * 8][tx] = W[(size_t)(k0 + ty + i * 8) * 1024 + n0 + tx];
  __syncthreads();
#pragma unroll
  for (int i = 0; i < 4; i++)
    T[(size_t)(n0 + ty + i * 8) * 1024 + k0 + tx] = f2b(tile[tx][ty + i * 8]);
}

// ---------- generic 128x128 bf16 GEMM, K=1024, B given transposed [n][k] ----------
// MODE 0: out = Qh bf16 [B,H,S,64]   MODE 1: out = Kh bf16 [B,H,S,64]
// MODE 2: out = Vt bf16 [B,H,64,S]   MODE 3: out = fp32 [4096][1024]
template <int MODE>
__global__ __launch_bounds__(256, 2) void gemm_k1024(
    const unsigned short* __restrict__ A, const unsigned short* __restrict__ Bt,
    const float* __restrict__ bias, void* __restrict__ Out) {
  __shared__ unsigned short As[128 * LDA];
  __shared__ unsigned short Bs[128 * LDA];
  const int t = threadIdx.x;
  const int wid = t >> 6, lane = t & 63;
  const int lrow = lane & 15, lquad = lane >> 4;
  const int m0 = blockIdx.x * 128, n0 = blockIdx.y * 128;
  const int wm = (wid & 1) * 64, wn = (wid >> 1) * 64;
  v4f zero = {0.f, 0.f, 0.f, 0.f};
  v4f acc[4][4];
#pragma unroll
  for (int i = 0; i < 4; i++)
#pragma unroll
    for (int j = 0; j < 4; j++) acc[i][j] = zero;

  for (int kt = 0; kt < 1024; kt += 64) {
    __syncthreads();
#pragma unroll
    for (int i = 0; i < 4; i++) {           // 128 rows x 8 col-groups
      int c = t + i * 256;
      int r = c >> 3, col8 = (c & 7) * 8;
      *(v8s*)&As[r * LDA + col8] = *(const v8s*)&A[(size_t)(m0 + r) * 1024 + kt + col8];
      *(v8s*)&Bs[r * LDA + col8] = *(const v8s*)&Bt[(size_t)(n0 + r) * 1024 + kt + col8];
    }
    __syncthreads();
#pragma unroll
    for (int k32 = 0; k32 < 64; k32 += 32) {
      v8s af[4], bfv[4];
#pragma unroll
      for (int mi = 0; mi < 4; mi++)
        af[mi] = *(const v8s*)&As[(wm + mi * 16 + lrow) * LDA + k32 + lquad * 8];
#pragma unroll
      for (int ni = 0; ni < 4; ni++)
        bfv[ni] = *(const v8s*)&Bs[(wn + ni * 16 + lrow) * LDA + k32 + lquad * 8];
#pragma unroll
      for (int mi = 0; mi < 4; mi++)
#pragma unroll
        for (int ni = 0; ni < 4; ni++)
          acc[mi][ni] = __builtin_amdgcn_mfma_f32_16x16x32_bf16(af[mi], bfv[ni], acc[mi][ni], 0, 0, 0);
    }
  }
#pragma unroll
  for (int mi = 0; mi < 4; mi++) {
#pragma unroll
    for (int ni = 0; ni < 4; ni++) {
      int gn = n0 + wn + ni * 16 + lrow;
      float bv = bias[gn];
#pragma unroll
      for (int r = 0; r < 4; r++) {
        int gm = m0 + wm + mi * 16 + lquad * 4 + r;
        float val = acc[mi][ni][r] + bv;
        if (MODE == 0 || MODE == 1) {
          int b = gm >> 10, s = gm & 1023, h = gn >> 6, d = gn & 63;
          ((unsigned short*)Out)[(size_t)((b * 16 + h) * 1024 + s) * 64 + d] = f2b(val);
        } else if (MODE == 2) {
          int b = gm >> 10, s = gm & 1023, h = gn >> 6, d = gn & 63;
          ((unsigned short*)Out)[(size_t)((b * 16 + h) * 64 + d) * 1024 + s] = f2b(val);
        } else {
          ((float*)Out)[(size_t)gm * 1024 + gn] = val;
        }
      }
    }
  }
}

// ---------- fused flash attention: raw logits out + online softmax + P@V ----------
// Per block: one (z = b*16+h, q-tile of 128). 4 waves, each owns 32 q-rows.
// QK^T computed with SWAPPED operands mfma(K,Q): acc regs hold 4 consecutive k
// -> raw logits stored as coalesced dwordx4; row stats reduce over lquad only.
__global__ __launch_bounds__(256, 2) void attn_fused_k(
    const unsigned short* __restrict__ Qh, const unsigned short* __restrict__ Kh,
    const unsigned short* __restrict__ Vt,
    const float* __restrict__ q_mask, const float* __restrict__ k_mask,
    float* __restrict__ attn, unsigned short* __restrict__ ctx) {
  __shared__ __align__(16) unsigned short Ks[128 * LDA];      // 18 KB
  __shared__ __align__(16) unsigned short Pl[4 * 32 * LDP];   // 34 KB (per-wave 32x128 P tile)
  __shared__ __align__(16) float Sl[4 * 32];                  // per-wave row scale/recip bcast
  const int z = blockIdx.x, b = z >> 4, h = z & 15;           // grid(64,8): same-z blocks
  const int q0 = blockIdx.y * 128;                            // stride 64 apart -> same XCD
  const int t = threadIdx.x, w = t >> 6, lane = t & 63;
  const int lrow = lane & 15, lq = lane >> 4;
  const unsigned short* Kz = Kh + (size_t)z * 1024 * 64;
  const unsigned short* Vz = Vt + (size_t)z * 64 * 1024;
  const float* km = k_mask + b * 1024;
  float* orow = attn + (size_t)z * 1024 * 1024;

  // Q fragments in registers (B-operand): lane holds q = q0+w*32+ni*16+lrow,
  // k = kb*32 + lq*8 + [0..7]
  v8s qf[2][2];
#pragma unroll
  for (int ni = 0; ni < 2; ni++)
#pragma unroll
    for (int kb = 0; kb < 2; kb++)
      qf[ni][kb] = *(const v8s*)&Qh[((size_t)z * 1024 + q0 + w * 32 + ni * 16 + lrow) * 64 + kb * 32 + lq * 8];

  v4f zero = {0.f, 0.f, 0.f, 0.f};
  v4f acc_c[2][4];
#pragma unroll
  for (int i = 0; i < 2; i++)
#pragma unroll
    for (int j = 0; j < 4; j++) acc_c[i][j] = zero;
  float m_run[2] = {-1e30f, -1e30f};
  float l_run[2] = {0.f, 0.f};

  for (int kt = 0; kt < 8; kt++) {
    __syncthreads();
    // stage K tile rows kt*128..+127 (all 4 waves cooperate)
#pragma unroll
    for (int i = 0; i < 4; i++) {
      int c = t + i * 256, r = c >> 3, col8 = (c & 7) * 8;
      *(v8s*)&Ks[r * LDA + col8] = *(const v8s*)&Kz[(size_t)(kt * 128 + r) * 64 + col8];
    }
    __syncthreads();
    // S^T tile: m = k (kt*128 + mi*16 + lq*4 + r), n = q (q0+w*32+ni*16+lrow)
    v4f sa[8][2];
#pragma unroll
    for (int mi = 0; mi < 8; mi++)
#pragma unroll
      for (int ni = 0; ni < 2; ni++) sa[mi][ni] = zero;
#pragma unroll
    for (int kb = 0; kb < 2; kb++) {
      v8s kf[8];
#pragma unroll
      for (int mi = 0; mi < 8; mi++)
        kf[mi] = *(const v8s*)&Ks[(mi * 16 + lrow) * LDA + kb * 32 + lq * 8];
#pragma unroll
      for (int mi = 0; mi < 8; mi++)
#pragma unroll
        for (int ni = 0; ni < 2; ni++)
          sa[mi][ni] = __builtin_amdgcn_mfma_f32_16x16x32_bf16(kf[mi], qf[ni][kb], sa[mi][ni], 0, 0, 0);
    }
    // raw logits: 16 B per lane per (mi,ni), 64 B-coalesced segments
#pragma unroll
    for (int mi = 0; mi < 8; mi++)
#pragma unroll
      for (int ni = 0; ni < 2; ni++)
        *(v4f*)&orow[(size_t)(q0 + w * 32 + ni * 16 + lrow) * 1024 + kt * 128 + mi * 16 + lq * 4] = sa[mi][ni];
    // k-mask bits for this lane's 32 k positions
    int msk[8];
#pragma unroll
    for (int mi = 0; mi < 8; mi++) {
      v4f kv = *(const v4f*)&km[kt * 128 + mi * 16 + lq * 4];
      msk[mi] = (kv[0] != 0.f ? 1 : 0) | (kv[1] != 0.f ? 2 : 0) |
                (kv[2] != 0.f ? 4 : 0) | (kv[3] != 0.f ? 8 : 0);
    }
    // online softmax per q-group ni
#pragma unroll
    for (int ni = 0; ni < 2; ni++) {
      float tmax = -1e30f;
#pragma unroll
      for (int mi = 0; mi < 8; mi++)
#pragma unroll
        for (int r = 0; r < 4; r++)
          if ((msk[mi] >> r) & 1) tmax = fmaxf(tmax, sa[mi][ni][r] * 0.125f);
      tmax = fmaxf(tmax, __shfl_xor(tmax, 16));
      tmax = fmaxf(tmax, __shfl_xor(tmax, 32));
      float mnew = fmaxf(m_run[ni], tmax);
      float tsum = 0.f;
#pragma unroll
      for (int mi = 0; mi < 8; mi++) {
        v4s pk;
#pragma unroll
        for (int r = 0; r < 4; r++) {
          float p = ((msk[mi] >> r) & 1) ? __expf(sa[mi][ni][r] * 0.125f - mnew) : 0.f;
          pk[r] = (short)f2b(p);
          tsum += p;
        }
        *(v4s*)&Pl[(w * 32 + ni * 16 + lrow) * LDP + mi * 16 + lq * 4] = pk;
      }
      tsum += __shfl_xor(tsum, 16);
      tsum += __shfl_xor(tsum, 32);
      float sc = __expf(m_run[ni] - mnew);   // ==1 when both -1e30
      l_run[ni] = l_run[ni] * sc + tsum;
      m_run[ni] = mnew;
      if (lq == 0) Sl[w * 32 + ni * 16 + lrow] = sc;
    }
    // wave-local fence: P + scale writes visible before cross-lane reads
    asm volatile("s_waitcnt lgkmcnt(0)" ::: "memory");
    // rescale C accumulator (scale indexed at C layout: q = miq*16 + lq*4 + r)
    v4f sc0 = *(const v4f*)&Sl[w * 32 + lq * 4];
    v4f sc1 = *(const v4f*)&Sl[w * 32 + 16 + lq * 4];
#pragma unroll
    for (int nd = 0; nd < 4; nd++)
#pragma unroll
      for (int r = 0; r < 4; r++) {
        acc_c[0][nd][r] *= sc0[r];
        acc_c[1][nd][r] *= sc1[r];
      }
    // P @ V: A = P from LDS, B = V from global (L2-resident Vt slice)
#pragma unroll
    for (int kk = 0; kk < 4; kk++) {
      v8s pa0 = *(const v8s*)&Pl[(w * 32 + lrow) * LDP + kk * 32 + lq * 8];
      v8s pa1 = *(const v8s*)&Pl[(w * 32 + 16 + lrow) * LDP + kk * 32 + lq * 8];
#pragma unroll
      for (int nd = 0; nd < 4; nd++) {
        v8s vb = *(const v8s*)&Vz[(size_t)(nd * 16 + lrow) * 1024 + kt * 128 + kk * 32 + lq * 8];
        acc_c[0][nd] = __builtin_amdgcn_mfma_f32_16x16x32_bf16(pa0, vb, acc_c[0][nd], 0, 0, 0);
        acc_c[1][nd] = __builtin_amdgcn_mfma_f32_16x16x32_bf16(pa1, vb, acc_c[1][nd], 0, 0, 0);
      }
    }
  }
  // epilogue: 1/l (0 for masked/empty rows), broadcast to C layout, store ctx
  float qm0 = q_mask[b * 1024 + q0 + w * 32 + lrow];
  float qm1 = q_mask[b * 1024 + q0 + w * 32 + 16 + lrow];
  float r0 = (m_run[0] > -1e29f && l_run[0] > 0.f && qm0 != 0.f) ? (1.f / l_run[0]) : 0.f;
  float r1 = (m_run[1] > -1e29f && l_run[1] > 0.f && qm1 != 0.f) ? (1.f / l_run[1]) : 0.f;
  if (lq == 0) {
    Sl[w * 32 + lrow] = r0;
    Sl[w * 32 + 16 + lrow] = r1;
  }
  asm volatile("s_waitcnt lgkmcnt(0)" ::: "memory");
  v4f rc0 = *(const v4f*)&Sl[w * 32 + lq * 4];
  v4f rc1 = *(const v4f*)&Sl[w * 32 + 16 + lq * 4];
#pragma unroll
  for (int miq = 0; miq < 2; miq++)
#pragma unroll
    for (int nd = 0; nd < 4; nd++)
#pragma unroll
      for (int r = 0; r < 4; r++) {
        int s = q0 + w * 32 + miq * 16 + lq * 4 + r;
        int d = nd * 16 + lrow;
        float rr = (miq == 0) ? rc0[r] : rc1[r];
        ctx[((size_t)(b * 1024 + s)) * 1024 + h * 64 + d] = f2b(acc_c[miq][nd][r] * rr);
      }
}

// ---------- residual + LayerNorm, one block per row ----------
__global__ __launch_bounds__(256) void resid_ln_k(
    const float* __restrict__ tmp, const float* __restrict__ resid,
    const float* __restrict__ gamma, const float* __restrict__ beta,
    float* __restrict__ out) {
  const int r = blockIdx.x, t = threadIdx.x;
  v4f x = *(const v4f*)(tmp + (size_t)r * 1024 + t * 4);
  v4f rv = *(const v4f*)(resid + (size_t)r * 1024 + t * 4);
  x = x + rv;
  float s = x[0] + x[1] + x[2] + x[3];
  float ss = x[0] * x[0] + x[1] * x[1] + x[2] * x[2] + x[3] * x[3];
#pragma unroll
  for (int off = 32; off; off >>= 1) { s += __shfl_xor(s, off); ss += __shfl_xor(ss, off); }
  __shared__ float red[8];
  const int wid = t >> 6, lane = t & 63;
  if (lane == 0) { red[wid] = s; red[4 + wid] = ss; }
  __syncthreads();
  s = red[0] + red[1] + red[2] + red[3];
  ss = red[4] + red[5] + red[6] + red[7];
  const float mu = s * (1.f / 1024.f);
  float var = ss * (1.f / 1024.f) - mu * mu;
  var = fmaxf(var, 0.f);
  const float rs = rsqrtf(var + 1e-5f);
  v4f g = *(const v4f*)(gamma + t * 4);
  v4f be = *(const v4f*)(beta + t * 4);
  v4f o = (x - mu) * rs * g + be;
  *(v4f*)(out + (size_t)r * 1024 + t * 4) = o;
}

extern "C" void kernel_launch(void* const* d_in, const int* in_sizes, int n_in,
                              void* d_out, int out_size, void* d_ws, size_t ws_size,
                              hipStream_t stream) {
  const float* q      = (const float*)d_in[0];
  const float* k      = (const float*)d_in[1];
  const float* v      = (const float*)d_in[2];
  const float* q_mask = (const float*)d_in[3];
  const float* k_mask = (const float*)d_in[4];
  const float* Wq = (const float*)d_in[5];
  const float* bq = (const float*)d_in[6];
  const float* Wk = (const float*)d_in[7];
  const float* bk = (const float*)d_in[8];
  const float* Wv = (const float*)d_in[9];
  const float* bv = (const float*)d_in[10];
  const float* Wf = (const float*)d_in[11];
  const float* bf = (const float*)d_in[12];
  const float* gamma = (const float*)d_in[13];
  const float* beta  = (const float*)d_in[14];

  float* out0 = (float*)d_out;
  float* attn = out0 + (size_t)MTOT * 1024;  // 64M fp32 raw logits

  char* w = (char*)d_ws;
  const size_t MB = (size_t)1 << 20;
  unsigned short* qb  = (unsigned short*)(w + 0);
  unsigned short* kb  = (unsigned short*)(w + 8 * MB);
  unsigned short* vb  = (unsigned short*)(w + 16 * MB);
  unsigned short* WqT = (unsigned short*)(w + 24 * MB);
  unsigned short* WkT = (unsigned short*)(w + 26 * MB);
  unsigned short* WvT = (unsigned short*)(w + 28 * MB);
  unsigned short* WfT = (unsigned short*)(w + 30 * MB);
  unsigned short* Qh  = (unsigned short*)(w + 32 * MB);
  unsigned short* Kh  = (unsigned short*)(w + 40 * MB);
  unsigned short* Vt  = (unsigned short*)(w + 48 * MB);
  unsigned short* ctx = (unsigned short*)(w + 0);        // reuse qb (dead after gemm<0>)
  float* tmp          = (float*)(w + 8 * MB);            // reuse kb+vb (16 MB)

  cast3_k<<<dim3(2048, 3), 256, 0, stream>>>(q, k, v, qb, kb, vb);
  transpose_cast_k<<<dim3(32, 32, 4), 256, 0, stream>>>(Wq, Wk, Wv, Wf, WqT, WkT, WvT, WfT);
  gemm_k1024<0><<<dim3(32, 8), 256, 0, stream>>>(qb, WqT, bq, Qh);
  gemm_k1024<1><<<dim3(32, 8), 256, 0, stream>>>(kb, WkT, bk, Kh);
  gemm_k1024<2><<<dim3(32, 8), 256, 0, stream>>>(vb, WvT, bv, Vt);
  attn_fused_k<<<dim3(64, 8), 256, 0, stream>>>(Qh, Kh, Vt, q_mask, k_mask, attn, ctx);
  gemm_k1024<3><<<dim3(32, 8), 256, 0, stream>>>(ctx, WfT, bf, tmp);
  resid_ln_k<<<4096, 256, 0, stream>>>(tmp, v, gamma, beta, out0);
}

// Round 2
// 482.845 us; speedup vs baseline: 1.3261x; 1.0981x over previous
//
#include <hip/hip_runtime.h>
#include <hip/hip_bf16.h>
#include <stdint.h>

// MultiHeadAttention: B=4, S=1024, D=1024, H=16, Dh=64
// d_out = [out (4M fp32)] ++ [attention raw logits (64M fp32)]

typedef __attribute__((ext_vector_type(8))) short v8s;   // 8 x bf16 bits
typedef __attribute__((ext_vector_type(4))) short v4s;   // 4 x bf16 bits
typedef __attribute__((ext_vector_type(4))) float v4f;

#define S_ 1024
#define MTOT 4096
#define LDA 72   // padded LDS row stride for attn kernel (bf16 elems)
#define LDP 136  // P-tile LDS row stride (bf16 elems)

// async global->LDS, 16B per lane; LDS dest = wave-uniform base + lane*16 (linear!)
#define GLD16(gp, lp)                                                              \
  __builtin_amdgcn_global_load_lds(                                                \
      (const __attribute__((address_space(1))) unsigned int*)(gp),                 \
      (__attribute__((address_space(3))) unsigned int*)(lp), 16, 0, 0)

__device__ __forceinline__ unsigned short f2b(float f) {
  union { float f; unsigned int u; } x; x.f = f;
  unsigned int u = x.u + 0x7fffu + ((x.u >> 16) & 1u);  // RNE
  return (unsigned short)(u >> 16);
}

// ---------- cast fp32 -> bf16 for q,k,v in one launch ----------
__global__ __launch_bounds__(256) void cast3_k(
    const float* __restrict__ q, const float* __restrict__ k, const float* __restrict__ v,
    unsigned short* __restrict__ qb, unsigned short* __restrict__ kb, unsigned short* __restrict__ vb) {
  const float* src = blockIdx.y == 0 ? q : blockIdx.y == 1 ? k : v;
  unsigned short* dst = blockIdx.y == 0 ? qb : blockIdx.y == 1 ? kb : vb;
  int i = (blockIdx.x * 256 + threadIdx.x) * 8;
  v4f a = *(const v4f*)(src + i);
  v4f b = *(const v4f*)(src + i + 4);
  union { unsigned short u[8]; v8s v; } o;
  o.u[0] = f2b(a[0]); o.u[1] = f2b(a[1]); o.u[2] = f2b(a[2]); o.u[3] = f2b(a[3]);
  o.u[4] = f2b(b[0]); o.u[5] = f2b(b[1]); o.u[6] = f2b(b[2]); o.u[7] = f2b(b[3]);
  *(v8s*)(dst + i) = o.v;
}

// ---------- transpose + cast W[k][n] -> WT[n][k] bf16 ----------
__global__ __launch_bounds__(256) void transpose_cast_k(
    const float* __restrict__ W0, const float* __restrict__ W1,
    const float* __restrict__ W2, const float* __restrict__ W3,
    unsigned short* __restrict__ T0, unsigned short* __restrict__ T1,
    unsigned short* __restrict__ T2, unsigned short* __restrict__ T3) {
  const float* W = blockIdx.z == 0 ? W0 : blockIdx.z == 1 ? W1 : blockIdx.z == 2 ? W2 : W3;
  unsigned short* T = blockIdx.z == 0 ? T0 : blockIdx.z == 1 ? T1 : blockIdx.z == 2 ? T2 : T3;
  __shared__ float tile[32][33];
  int tx = threadIdx.x & 31, ty = threadIdx.x >> 5;
  int n0 = blockIdx.x * 32, k0 = blockIdx.y * 32;
#pragma unroll
  for (int i = 0; i < 4; i++)
    tile[ty + i * 8][tx] = W[(size_t)(k0 + ty + i * 8) * 1024 + n0 + tx];
  __syncthreads();
#pragma unroll
  for (int i = 0; i < 4; i++)
    T[(size_t)(n0 + ty + i * 8) * 1024 + k0 + tx] = f2b(tile[tx][ty + i * 8]);
}

// ---------- merged QKV projection: grid (32, 8, 3), m97-style staging ----------
// z=0: Qh [B,H,S,64]  z=1: Kh [B,H,S,64]  z=2: Vt [B,H,64,S]
__global__ __launch_bounds__(256, 2) void qkv_gemm_k(
    const unsigned short* __restrict__ qb, const unsigned short* __restrict__ kb,
    const unsigned short* __restrict__ vb,
    const unsigned short* __restrict__ WqT, const unsigned short* __restrict__ WkT,
    const unsigned short* __restrict__ WvT,
    const float* __restrict__ bq, const float* __restrict__ bk, const float* __restrict__ bv,
    unsigned short* __restrict__ Qh, unsigned short* __restrict__ Kh,
    unsigned short* __restrict__ Vt) {
  __shared__ __align__(16) unsigned short As[128 * 64];
  __shared__ __align__(16) unsigned short Bs[128 * 64];
  const int z = blockIdx.z;
  const unsigned short* A  = z == 0 ? qb : z == 1 ? kb : vb;
  const unsigned short* Bt = z == 0 ? WqT : z == 1 ? WkT : WvT;
  const float* bias        = z == 0 ? bq : z == 1 ? bk : bv;
  unsigned short* Out      = z == 0 ? Qh : z == 1 ? Kh : Vt;
  const int t = threadIdx.x;
  const int wid = t >> 6, lane = t & 63;
  const int lrow = lane & 15, lquad = lane >> 4;
  const int m0 = blockIdx.x * 128, n0 = blockIdx.y * 128;
  const int wm = (wid & 1) * 64, wn = (wid >> 1) * 64;
  v4f zero = {0.f, 0.f, 0.f, 0.f};
  v4f acc[4][4];
#pragma unroll
  for (int i = 0; i < 4; i++)
#pragma unroll
    for (int j = 0; j < 4; j++) acc[i][j] = zero;

  for (int kt = 0; kt < 1024; kt += 64) {
    __syncthreads();
#pragma unroll
    for (int i = 0; i < 4; i++) {
      int c = t + i * 256;                  // 0..1023
      int r = c >> 3, col8 = (c & 7) * 8;   // LDS byte off = c*16 (linear)
      GLD16(&A[(size_t)(m0 + r) * 1024 + kt + col8], &As[c * 8]);
      GLD16(&Bt[(size_t)(n0 + r) * 1024 + kt + col8], &Bs[c * 8]);
    }
    __syncthreads();
#pragma unroll
    for (int k32 = 0; k32 < 64; k32 += 32) {
      v8s af[4], bfv[4];
#pragma unroll
      for (int mi = 0; mi < 4; mi++)
        af[mi] = *(const v8s*)&As[(wm + mi * 16 + lrow) * 64 + k32 + lquad * 8];
#pragma unroll
      for (int ni = 0; ni < 4; ni++)
        bfv[ni] = *(const v8s*)&Bs[(wn + ni * 16 + lrow) * 64 + k32 + lquad * 8];
#pragma unroll
      for (int mi = 0; mi < 4; mi++)
#pragma unroll
        for (int ni = 0; ni < 4; ni++)
          acc[mi][ni] = __builtin_amdgcn_mfma_f32_16x16x32_bf16(af[mi], bfv[ni], acc[mi][ni], 0, 0, 0);
    }
  }
#pragma unroll
  for (int mi = 0; mi < 4; mi++) {
#pragma unroll
    for (int ni = 0; ni < 4; ni++) {
      int gn = n0 + wn + ni * 16 + lrow;
      float bv_ = bias[gn];
#pragma unroll
      for (int r = 0; r < 4; r++) {
        int gm = m0 + wm + mi * 16 + lquad * 4 + r;
        float val = acc[mi][ni][r] + bv_;
        int b = gm >> 10, s = gm & 1023, h = gn >> 6, d = gn & 63;
        if (z < 2)
          Out[(size_t)((b * 16 + h) * 1024 + s) * 64 + d] = f2b(val);
        else
          Out[(size_t)((b * 16 + h) * 64 + d) * 1024 + s] = f2b(val);
      }
    }
  }
}

// ---------- output projection, split-K: grid (32, 8, 2) ----------
// z=0: K 0..512 -> tmp0   z=1: K 512..1024 -> tmp1   (bias added in resid_ln)
__global__ __launch_bounds__(256, 2) void fgemm_k(
    const unsigned short* __restrict__ A, const unsigned short* __restrict__ Bt,
    float* __restrict__ tmp0, float* __restrict__ tmp1) {
  __shared__ __align__(16) unsigned short As[128 * 64];
  __shared__ __align__(16) unsigned short Bs[128 * 64];
  const int z = blockIdx.z;
  float* Out = z == 0 ? tmp0 : tmp1;
  const int t = threadIdx.x;
  const int wid = t >> 6, lane = t & 63;
  const int lrow = lane & 15, lquad = lane >> 4;
  const int m0 = blockIdx.x * 128, n0 = blockIdx.y * 128;
  const int wm = (wid & 1) * 64, wn = (wid >> 1) * 64;
  v4f zero = {0.f, 0.f, 0.f, 0.f};
  v4f acc[4][4];
#pragma unroll
  for (int i = 0; i < 4; i++)
#pragma unroll
    for (int j = 0; j < 4; j++) acc[i][j] = zero;

  for (int kt = z * 512; kt < z * 512 + 512; kt += 64) {
    __syncthreads();
#pragma unroll
    for (int i = 0; i < 4; i++) {
      int c = t + i * 256;
      int r = c >> 3, col8 = (c & 7) * 8;
      GLD16(&A[(size_t)(m0 + r) * 1024 + kt + col8], &As[c * 8]);
      GLD16(&Bt[(size_t)(n0 + r) * 1024 + kt + col8], &Bs[c * 8]);
    }
    __syncthreads();
#pragma unroll
    for (int k32 = 0; k32 < 64; k32 += 32) {
      v8s af[4], bfv[4];
#pragma unroll
      for (int mi = 0; mi < 4; mi++)
        af[mi] = *(const v8s*)&As[(wm + mi * 16 + lrow) * 64 + k32 + lquad * 8];
#pragma unroll
      for (int ni = 0; ni < 4; ni++)
        bfv[ni] = *(const v8s*)&Bs[(wn + ni * 16 + lrow) * 64 + k32 + lquad * 8];
#pragma unroll
      for (int mi = 0; mi < 4; mi++)
#pragma unroll
        for (int ni = 0; ni < 4; ni++)
          acc[mi][ni] = __builtin_amdgcn_mfma_f32_16x16x32_bf16(af[mi], bfv[ni], acc[mi][ni], 0, 0, 0);
    }
  }
#pragma unroll
  for (int mi = 0; mi < 4; mi++)
#pragma unroll
    for (int ni = 0; ni < 4; ni++) {
      int gn = n0 + wn + ni * 16 + lrow;
#pragma unroll
      for (int r = 0; r < 4; r++) {
        int gm = m0 + wm + mi * 16 + lquad * 4 + r;
        Out[(size_t)gm * 1024 + gn] = acc[mi][ni][r];
      }
    }
}

// ---------- fused flash attention: raw logits out + online softmax + P@V ----------
__global__ __launch_bounds__(256, 2) void attn_fused_k(
    const unsigned short* __restrict__ Qh, const unsigned short* __restrict__ Kh,
    const unsigned short* __restrict__ Vt,
    const float* __restrict__ q_mask, const float* __restrict__ k_mask,
    float* __restrict__ attn, unsigned short* __restrict__ ctx) {
  __shared__ __align__(16) unsigned short Ks[128 * LDA];      // 18 KB
  __shared__ __align__(16) unsigned short Pl[4 * 32 * LDP];   // 34 KB
  __shared__ __align__(16) float Sl[4 * 32];
  const int z = blockIdx.x, b = z >> 4, h = z & 15;
  const int q0 = blockIdx.y * 128;
  const int t = threadIdx.x, w = t >> 6, lane = t & 63;
  const int lrow = lane & 15, lq = lane >> 4;
  const unsigned short* Kz = Kh + (size_t)z * 1024 * 64;
  const unsigned short* Vz = Vt + (size_t)z * 64 * 1024;
  const float* km = k_mask + b * 1024;
  float* orow = attn + (size_t)z * 1024 * 1024;

  v8s qf[2][2];
#pragma unroll
  for (int ni = 0; ni < 2; ni++)
#pragma unroll
    for (int kb = 0; kb < 2; kb++)
      qf[ni][kb] = *(const v8s*)&Qh[((size_t)z * 1024 + q0 + w * 32 + ni * 16 + lrow) * 64 + kb * 32 + lq * 8];

  v4f zero = {0.f, 0.f, 0.f, 0.f};
  v4f acc_c[2][4];
#pragma unroll
  for (int i = 0; i < 2; i++)
#pragma unroll
    for (int j = 0; j < 4; j++) acc_c[i][j] = zero;
  float m_run[2] = {-1e30f, -1e30f};
  float l_run[2] = {0.f, 0.f};

  for (int kt = 0; kt < 8; kt++) {
    __syncthreads();
#pragma unroll
    for (int i = 0; i < 4; i++) {
      int c = t + i * 256, r = c >> 3, col8 = (c & 7) * 8;
      *(v8s*)&Ks[r * LDA + col8] = *(const v8s*)&Kz[(size_t)(kt * 128 + r) * 64 + col8];
    }
    __syncthreads();
    v4f sa[8][2];
#pragma unroll
    for (int mi = 0; mi < 8; mi++)
#pragma unroll
      for (int ni = 0; ni < 2; ni++) sa[mi][ni] = zero;
#pragma unroll
    for (int kb = 0; kb < 2; kb++) {
      v8s kf[8];
#pragma unroll
      for (int mi = 0; mi < 8; mi++)
        kf[mi] = *(const v8s*)&Ks[(mi * 16 + lrow) * LDA + kb * 32 + lq * 8];
#pragma unroll
      for (int mi = 0; mi < 8; mi++)
#pragma unroll
        for (int ni = 0; ni < 2; ni++)
          sa[mi][ni] = __builtin_amdgcn_mfma_f32_16x16x32_bf16(kf[mi], qf[ni][kb], sa[mi][ni], 0, 0, 0);
    }
#pragma unroll
    for (int mi = 0; mi < 8; mi++)
#pragma unroll
      for (int ni = 0; ni < 2; ni++)
        *(v4f*)&orow[(size_t)(q0 + w * 32 + ni * 16 + lrow) * 1024 + kt * 128 + mi * 16 + lq * 4] = sa[mi][ni];
    int msk[8];
#pragma unroll
    for (int mi = 0; mi < 8; mi++) {
      v4f kv = *(const v4f*)&km[kt * 128 + mi * 16 + lq * 4];
      msk[mi] = (kv[0] != 0.f ? 1 : 0) | (kv[1] != 0.f ? 2 : 0) |
                (kv[2] != 0.f ? 4 : 0) | (kv[3] != 0.f ? 8 : 0);
    }
#pragma unroll
    for (int ni = 0; ni < 2; ni++) {
      float tmax = -1e30f;
#pragma unroll
      for (int mi = 0; mi < 8; mi++)
#pragma unroll
        for (int r = 0; r < 4; r++)
          if ((msk[mi] >> r) & 1) tmax = fmaxf(tmax, sa[mi][ni][r] * 0.125f);
      tmax = fmaxf(tmax, __shfl_xor(tmax, 16));
      tmax = fmaxf(tmax, __shfl_xor(tmax, 32));
      float mnew = fmaxf(m_run[ni], tmax);
      float tsum = 0.f;
#pragma unroll
      for (int mi = 0; mi < 8; mi++) {
        v4s pk;
#pragma unroll
        for (int r = 0; r < 4; r++) {
          float p = ((msk[mi] >> r) & 1) ? __expf(sa[mi][ni][r] * 0.125f - mnew) : 0.f;
          pk[r] = (short)f2b(p);
          tsum += p;
        }
        *(v4s*)&Pl[(w * 32 + ni * 16 + lrow) * LDP + mi * 16 + lq * 4] = pk;
      }
      tsum += __shfl_xor(tsum, 16);
      tsum += __shfl_xor(tsum, 32);
      float sc = __expf(m_run[ni] - mnew);
      l_run[ni] = l_run[ni] * sc + tsum;
      m_run[ni] = mnew;
      if (lq == 0) Sl[w * 32 + ni * 16 + lrow] = sc;
    }
    asm volatile("s_waitcnt lgkmcnt(0)" ::: "memory");
    v4f sc0 = *(const v4f*)&Sl[w * 32 + lq * 4];
    v4f sc1 = *(const v4f*)&Sl[w * 32 + 16 + lq * 4];
#pragma unroll
    for (int nd = 0; nd < 4; nd++)
#pragma unroll
      for (int r = 0; r < 4; r++) {
        acc_c[0][nd][r] *= sc0[r];
        acc_c[1][nd][r] *= sc1[r];
      }
#pragma unroll
    for (int kk = 0; kk < 4; kk++) {
      v8s pa0 = *(const v8s*)&Pl[(w * 32 + lrow) * LDP + kk * 32 + lq * 8];
      v8s pa1 = *(const v8s*)&Pl[(w * 32 + 16 + lrow) * LDP + kk * 32 + lq * 8];
#pragma unroll
      for (int nd = 0; nd < 4; nd++) {
        v8s vb = *(const v8s*)&Vz[(size_t)(nd * 16 + lrow) * 1024 + kt * 128 + kk * 32 + lq * 8];
        acc_c[0][nd] = __builtin_amdgcn_mfma_f32_16x16x32_bf16(pa0, vb, acc_c[0][nd], 0, 0, 0);
        acc_c[1][nd] = __builtin_amdgcn_mfma_f32_16x16x32_bf16(pa1, vb, acc_c[1][nd], 0, 0, 0);
      }
    }
  }
  float qm0 = q_mask[b * 1024 + q0 + w * 32 + lrow];
  float qm1 = q_mask[b * 1024 + q0 + w * 32 + 16 + lrow];
  float r0 = (m_run[0] > -1e29f && l_run[0] > 0.f && qm0 != 0.f) ? (1.f / l_run[0]) : 0.f;
  float r1 = (m_run[1] > -1e29f && l_run[1] > 0.f && qm1 != 0.f) ? (1.f / l_run[1]) : 0.f;
  if (lq == 0) {
    Sl[w * 32 + lrow] = r0;
    Sl[w * 32 + 16 + lrow] = r1;
  }
  asm volatile("s_waitcnt lgkmcnt(0)" ::: "memory");
  v4f rc0 = *(const v4f*)&Sl[w * 32 + lq * 4];
  v4f rc1 = *(const v4f*)&Sl[w * 32 + 16 + lq * 4];
#pragma unroll
  for (int miq = 0; miq < 2; miq++)
#pragma unroll
    for (int nd = 0; nd < 4; nd++)
#pragma unroll
      for (int r = 0; r < 4; r++) {
        int s = q0 + w * 32 + miq * 16 + lq * 4 + r;
        int d = nd * 16 + lrow;
        float rr = (miq == 0) ? rc0[r] : rc1[r];
        ctx[((size_t)(b * 1024 + s)) * 1024 + h * 64 + d] = f2b(acc_c[miq][nd][r] * rr);
      }
}

// ---------- residual + bias + split-K combine + LayerNorm ----------
__global__ __launch_bounds__(256) void resid_ln_k(
    const float* __restrict__ tmp0, const float* __restrict__ tmp1,
    const float* __restrict__ bf, const float* __restrict__ resid,
    const float* __restrict__ gamma, const float* __restrict__ beta,
    float* __restrict__ out) {
  const int r = blockIdx.x, t = threadIdx.x;
  v4f x0 = *(const v4f*)(tmp0 + (size_t)r * 1024 + t * 4);
  v4f x1 = *(const v4f*)(tmp1 + (size_t)r * 1024 + t * 4);
  v4f bv = *(const v4f*)(bf + t * 4);
  v4f rv = *(const v4f*)(resid + (size_t)r * 1024 + t * 4);
  v4f x = x0 + x1 + bv + rv;
  float s = x[0] + x[1] + x[2] + x[3];
  float ss = x[0] * x[0] + x[1] * x[1] + x[2] * x[2] + x[3] * x[3];
#pragma unroll
  for (int off = 32; off; off >>= 1) { s += __shfl_xor(s, off); ss += __shfl_xor(ss, off); }
  __shared__ float red[8];
  const int wid = t >> 6, lane = t & 63;
  if (lane == 0) { red[wid] = s; red[4 + wid] = ss; }
  __syncthreads();
  s = red[0] + red[1] + red[2] + red[3];
  ss = red[4] + red[5] + red[6] + red[7];
  const float mu = s * (1.f / 1024.f);
  float var = ss * (1.f / 1024.f) - mu * mu;
  var = fmaxf(var, 0.f);
  const float rs = rsqrtf(var + 1e-5f);
  v4f g = *(const v4f*)(gamma + t * 4);
  v4f be = *(const v4f*)(beta + t * 4);
  v4f o = (x - mu) * rs * g + be;
  *(v4f*)(out + (size_t)r * 1024 + t * 4) = o;
}

extern "C" void kernel_launch(void* const* d_in, const int* in_sizes, int n_in,
                              void* d_out, int out_size, void* d_ws, size_t ws_size,
                              hipStream_t stream) {
  const float* q      = (const float*)d_in[0];
  const float* k      = (const float*)d_in[1];
  const float* v      = (const float*)d_in[2];
  const float* q_mask = (const float*)d_in[3];
  const float* k_mask = (const float*)d_in[4];
  const float* Wq = (const float*)d_in[5];
  const float* bq = (const float*)d_in[6];
  const float* Wk = (const float*)d_in[7];
  const float* bk = (const float*)d_in[8];
  const float* Wv = (const float*)d_in[9];
  const float* bv = (const float*)d_in[10];
  const float* Wf = (const float*)d_in[11];
  const float* bf = (const float*)d_in[12];
  const float* gamma = (const float*)d_in[13];
  const float* beta  = (const float*)d_in[14];

  float* out0 = (float*)d_out;
  float* attn = out0 + (size_t)MTOT * 1024;  // 64M fp32 raw logits

  char* w = (char*)d_ws;
  const size_t MB = (size_t)1 << 20;
  unsigned short* qb  = (unsigned short*)(w + 0);
  unsigned short* kb  = (unsigned short*)(w + 8 * MB);
  unsigned short* vb  = (unsigned short*)(w + 16 * MB);
  unsigned short* WqT = (unsigned short*)(w + 24 * MB);
  unsigned short* WkT = (unsigned short*)(w + 26 * MB);
  unsigned short* WvT = (unsigned short*)(w + 28 * MB);
  unsigned short* WfT = (unsigned short*)(w + 30 * MB);
  unsigned short* Qh  = (unsigned short*)(w + 32 * MB);
  unsigned short* Kh  = (unsigned short*)(w + 40 * MB);
  unsigned short* Vt  = (unsigned short*)(w + 48 * MB);
  unsigned short* ctx = (unsigned short*)(w + 0);        // reuse qb (dead after qkv_gemm)
  float* tmp0         = (float*)(w + 8 * MB);            // reuse kb+vb (16 MB)
  float* tmp1         = (float*)(w + 32 * MB);           // reuse Qh+Kh (16 MB)

  cast3_k<<<dim3(2048, 3), 256, 0, stream>>>(q, k, v, qb, kb, vb);
  transpose_cast_k<<<dim3(32, 32, 4), 256, 0, stream>>>(Wq, Wk, Wv, Wf, WqT, WkT, WvT, WfT);
  qkv_gemm_k<<<dim3(32, 8, 3), 256, 0, stream>>>(qb, kb, vb, WqT, WkT, WvT, bq, bk, bv, Qh, Kh, Vt);
  attn_fused_k<<<dim3(64, 8), 256, 0, stream>>>(Qh, Kh, Vt, q_mask, k_mask, attn, ctx);
  fgemm_k<<<dim3(32, 8, 2), 256, 0, stream>>>(ctx, WfT, tmp0, tmp1);
  resid_ln_k<<<4096, 256, 0, stream>>>(tmp0, tmp1, bf, v, gamma, beta, out0);
}